// Round 8
// baseline (293.695 us; speedup 1.0000x reference)
//
#include <hip/hip_runtime.h>
#include <math.h>

#define BATCH 2
#define SEQ   2048
#define DIM   1024
#define NST   16
#define DTR   64
#define KSL   8                     // split-K slices for x_proj

typedef _Float16 f16x8 __attribute__((ext_vector_type(8)));
typedef float f32x4 __attribute__((ext_vector_type(4)));

__device__ __forceinline__ float softplus_f(float v) {
  return fmaxf(v, 0.f) + log1pf(expf(-fabsf(v)));
}

__device__ __forceinline__ void gl_lds16(const _Float16* g, _Float16* l) {
  __builtin_amdgcn_global_load_lds(
      (const __attribute__((address_space(1))) void*)g,
      (__attribute__((address_space(3))) void*)l, 16, 0, 0);
}

// raw barrier: LDS-ops drained, but vmcnt (in-flight global loads) NOT drained
__device__ __forceinline__ void raw_lds_barrier() {
  asm volatile("s_waitcnt lgkmcnt(0)" ::: "memory");
  __builtin_amdgcn_sched_barrier(0);
  __builtin_amdgcn_s_barrier();
  __builtin_amdgcn_sched_barrier(0);
}

// DPP move with explicit fallback (old) for invalid source lanes.
template <int CTRL, int RMASK>
__device__ __forceinline__ float dpp_mov(float oldv, float src) {
  return __int_as_float(__builtin_amdgcn_update_dpp(
      __float_as_int(oldv), __float_as_int(src), CTRL, RMASK, 0xf, false));
}

#define FMA_ROW(i, av)                                        \
  acc[i][0] = fmaf(av, b.x, acc[i][0]);                       \
  acc[i][1] = fmaf(av, b.y, acc[i][1]);                       \
  acc[i][2] = fmaf(av, b.z, acc[i][2]);                       \
  acc[i][3] = fmaf(av, b.w, acc[i][3]);

// ---------------- split fp32 -> hi/lo f16 planes (weights only) -------------
__global__ __launch_bounds__(256) void k_cvt2(
    const float* __restrict__ in1, _Float16* __restrict__ hi1,
    _Float16* __restrict__ lo1,                       // in_proj_w: 1024 blocks
    const float* __restrict__ in2, _Float16* __restrict__ hi2,
    _Float16* __restrict__ lo2) {                     // out_proj_w: 512 blocks
  int bb = blockIdx.x;
  const float* in;
  _Float16 *hi, *lo;
  if (bb < 1024) {
    in = in1; hi = hi1; lo = lo1;
  } else {
    in = in2; hi = hi2; lo = lo2; bb -= 1024;
  }
  const int i = (bb * 256 + threadIdx.x) * 8;
  const float4 a = *(const float4*)(in + i);
  const float4 b = *(const float4*)(in + i + 4);
  const float v[8] = {a.x, a.y, a.z, a.w, b.x, b.y, b.z, b.w};
  f16x8 h, l;
#pragma unroll
  for (int j = 0; j < 8; ++j) {
    const _Float16 hh = (_Float16)v[j];
    h[j] = hh;
    l[j] = (_Float16)(v[j] - (float)hh);
  }
  *(f16x8*)(hi + i) = h;
  *(f16x8*)(lo + i) = l;
}

// ---------------- f16x3 NT GEMM: D[m][n] = sum_k A[m,k]*B[n,k], K=LD=1024 ----
// EPI=0: A,B both pre-split f16 planes; 2-phase gl_lds ping-pong (proven path).
// EPI=1: B comes from fp32 x directly — global->reg->cvt->ds_write staging.
//        WRITEB is hoisted INTO the compute phase (after fragment ds_reads,
//        before MFMAs): buffer cur^1's readers all finished before the k-1
//        raw barrier, so the write is safe there, and the cvt VALU overlaps
//        MFMA issue instead of serializing between barriers.
template <int EPI>
__global__ __launch_bounds__(256) void kgemm_f16x3(
    const _Float16* __restrict__ Ah, const _Float16* __restrict__ Al,
    const _Float16* __restrict__ Bh, const _Float16* __restrict__ Bl,
    const float* __restrict__ Bx,
    float* __restrict__ out0, float* __restrict__ out1) {
  __shared__ _Float16 sm[32768];  // 64 KB: 2 buffers x (Ah|Al|Bh|Bl) 128x32
  const int tid = threadIdx.x;
  const int wid = tid >> 6, lane = tid & 63;
  const int wm = wid >> 1, wn = wid & 1;
  const int m0 = blockIdx.y * 128;
  const int n0 = blockIdx.x * 128;

  const int r0 = wid * 32;
  const int srow = lane >> 2;
  // staging source: chunk (lane&3) ^ swz, swz = (row>>1)&3 = (lane>>3)&3
  const int skqs = ((lane & 3) ^ ((lane >> 3) & 3)) * 8;
  const _Float16* gAh = Ah + (size_t)(m0 + r0 + srow) * 1024 + skqs;
  const _Float16* gAl = Al + (size_t)(m0 + r0 + srow) * 1024 + skqs;

  const int fr = lane & 15;
  // fragment read: desired chunk (lane>>4), stored at chunk^((row>>1)&3)
  const int fks = (((lane >> 4) ^ ((fr >> 1) & 3))) * 8;

  f32x4 acc[4][4];
#pragma unroll
  for (int i = 0; i < 4; ++i)
#pragma unroll
    for (int j = 0; j < 4; ++j) acc[i][j] = (f32x4)(0.f);

  if constexpr (EPI == 0) {
    // ---------------- proven gl_lds ping-pong path ----------------
    const _Float16* gBh = Bh + (size_t)(n0 + r0 + srow) * 1024 + skqs;
    const _Float16* gBl = Bl + (size_t)(n0 + r0 + srow) * 1024 + skqs;
    auto STAGE = [&](int buf, int k0) {
      _Float16* base = sm + buf * 16384;
      _Float16* lA = base + r0 * 32;
      gl_lds16(gAh + k0, lA);
      gl_lds16(gAh + k0 + 16 * 1024, lA + 512);
      gl_lds16(gAl + k0, lA + 4096);
      gl_lds16(gAl + k0 + 16 * 1024, lA + 4096 + 512);
      gl_lds16(gBh + k0, lA + 8192);
      gl_lds16(gBh + k0 + 16 * 1024, lA + 8192 + 512);
      gl_lds16(gBl + k0, lA + 12288);
      gl_lds16(gBl + k0 + 16 * 1024, lA + 12288 + 512);
    };
    STAGE(0, 0);
    int cur = 0;
    for (int k0 = 0; k0 < 1024; k0 += 32) {
      __syncthreads();
      if (k0 + 32 < 1024) STAGE(cur ^ 1, k0 + 32);
      const _Float16* base = sm + cur * 16384;
      f16x8 ah[4], alo[4], bh[4], blo[4];
#pragma unroll
      for (int i = 0; i < 4; ++i) {
        const int ao = (wm * 64 + i * 16 + fr) * 32 + fks;
        const int bo = (wn * 64 + i * 16 + fr) * 32 + fks;
        ah[i]  = *(const f16x8*)(base + ao);
        alo[i] = *(const f16x8*)(base + 4096 + ao);
        bh[i]  = *(const f16x8*)(base + 8192 + bo);
        blo[i] = *(const f16x8*)(base + 12288 + bo);
      }
#pragma unroll
      for (int i = 0; i < 4; ++i)
#pragma unroll
        for (int j = 0; j < 4; ++j) {
          acc[i][j] = __builtin_amdgcn_mfma_f32_16x16x32_f16(
              ah[i], bh[j], acc[i][j], 0, 0, 0);
          acc[i][j] = __builtin_amdgcn_mfma_f32_16x16x32_f16(
              ah[i], blo[j], acc[i][j], 0, 0, 0);
          acc[i][j] = __builtin_amdgcn_mfma_f32_16x16x32_f16(
              alo[i], bh[j], acc[i][j], 0, 0, 0);
        }
      cur ^= 1;
    }
  } else {
    // ---------------- fused-cvt path: B from fp32 x ----------------
    const float* gBx =
        Bx + (size_t)(n0 + r0 + srow) * 1024 + (lane & 3) * 8;  // unswizzled
    const int wchunk = skqs;  // same XOR as gl_lds source pre-swizzle
    float4 brg[4];            // B regs: rows srow, srow+16 x 8 f32

    auto LOADB = [&](int k0) {
      brg[0] = *(const float4*)(gBx + k0);
      brg[1] = *(const float4*)(gBx + k0 + 4);
      brg[2] = *(const float4*)(gBx + k0 + 16 * 1024);
      brg[3] = *(const float4*)(gBx + k0 + 16 * 1024 + 4);
    };
    auto STAGE_A = [&](int buf, int k0) {
      _Float16* base = sm + buf * 16384;
      _Float16* lA = base + r0 * 32;
      gl_lds16(gAh + k0, lA);
      gl_lds16(gAh + k0 + 16 * 1024, lA + 512);
      gl_lds16(gAl + k0, lA + 4096);
      gl_lds16(gAl + k0 + 16 * 1024, lA + 4096 + 512);
    };
    auto WRITEB = [&](int buf) {
      _Float16* bB = sm + buf * 16384 + 8192 + r0 * 32;
#pragma unroll
      for (int h = 0; h < 2; ++h) {
        const float v[8] = {brg[2 * h].x,     brg[2 * h].y,
                            brg[2 * h].z,     brg[2 * h].w,
                            brg[2 * h + 1].x, brg[2 * h + 1].y,
                            brg[2 * h + 1].z, brg[2 * h + 1].w};
        f16x8 hv, lv;
#pragma unroll
        for (int j = 0; j < 8; ++j) {
          const _Float16 hh = (_Float16)v[j];
          hv[j] = hh;
          lv[j] = (_Float16)(v[j] - (float)hh);
        }
        const int off = (srow + 16 * h) * 32 + wchunk;
        *(f16x8*)(bB + off) = hv;            // Bh plane
        *(f16x8*)(bB + 4096 + off) = lv;     // Bl plane
      }
    };

    // prologue
    LOADB(0);
    STAGE_A(0, 0);
    __syncthreads();           // A(0) landed, B(0) regs ready
    WRITEB(0);
    LOADB(32);
    STAGE_A(1, 32);
    raw_lds_barrier();         // B(0) visible; A(1)/B(1) stay in flight

    int cur = 0;
    for (int k = 0; k < 32; ++k) {
      const _Float16* base = sm + cur * 16384;
      f16x8 ah[4], alo[4], bh[4], blo[4];
#pragma unroll
      for (int i = 0; i < 4; ++i) {
        const int ao = (wm * 64 + i * 16 + fr) * 32 + fks;
        const int bo = (wn * 64 + i * 16 + fr) * 32 + fks;
        ah[i]  = *(const f16x8*)(base + ao);
        alo[i] = *(const f16x8*)(base + 4096 + ao);
        bh[i]  = *(const f16x8*)(base + 8192 + bo);
        blo[i] = *(const f16x8*)(base + 12288 + bo);
      }
      // B(k+1) cvt+write into cur^1, overlapped with MFMA below: cur^1's
      // readers all passed the k-1 raw barrier, so this is ordering-safe.
      if (k < 31) WRITEB(cur ^ 1);
#pragma unroll
      for (int i = 0; i < 4; ++i)
#pragma unroll
        for (int j = 0; j < 4; ++j) {
          acc[i][j] = __builtin_amdgcn_mfma_f32_16x16x32_f16(
              ah[i], bh[j], acc[i][j], 0, 0, 0);
          acc[i][j] = __builtin_amdgcn_mfma_f32_16x16x32_f16(
              ah[i], blo[j], acc[i][j], 0, 0, 0);
          acc[i][j] = __builtin_amdgcn_mfma_f32_16x16x32_f16(
              alo[i], bh[j], acc[i][j], 0, 0, 0);
        }
      if (k < 31) {
        __syncthreads();       // all waves done reading cur; B(k+1) written
        if (k + 2 < 32) {
          LOADB((k + 2) * 32);          // B(k+2) -> regs (in flight)
          STAGE_A(cur, (k + 2) * 32);   // A(k+2) -> cur (in flight)
        }
        raw_lds_barrier();     // B writes visible; new loads keep flying
      }
      cur ^= 1;
    }
  }

  const int lr4 = (lane >> 4) * 4, lc = lane & 15;
#pragma unroll
  for (int i = 0; i < 4; ++i) {
#pragma unroll
    for (int j = 0; j < 4; ++j) {
      const int ar = m0 + wm * 64 + i * 16 + lr4;
      const int bc = n0 + wn * 64 + j * 16 + lc;
#pragma unroll
      for (int r = 0; r < 4; ++r) {
        const float v = acc[i][j][r];
        if (EPI == 0) {
          out0[(size_t)(ar + r) * 1024 + bc] = v;
        } else {
          const int bb = bc >> 11, tt = bc & 2047;
          if (ar < 1024) {
            out0[((size_t)bb * 1024 + ar + r) * 2048 + tt] = v;
          } else {
            out1[((size_t)bb * 1024 + (ar + r - 1024)) * 2048 + tt] = v;
          }
        }
      }
    }
  }
}

// ---------------- conv: depthwise k=3, pad=1, along t ----------------
__global__ __launch_bounds__(256) void k_conv(
    const float* __restrict__ xcraw, const float* __restrict__ cw,
    const float* __restrict__ cb, float* __restrict__ xc) {
  const int idx = blockIdx.x * 256 + threadIdx.x;
  const int t0 = (idx & (SEQ / 4 - 1)) * 4;
  const int r = idx >> 9;  // b*DIM + d
  const int d = r & (DIM - 1);
  const float w0 = cw[d * 3 + 0], w1 = cw[d * 3 + 1], w2 = cw[d * 3 + 2];
  const float bias = cb[d];
  const float* in = xcraw + (size_t)r * SEQ;
  float o[4];
#pragma unroll
  for (int j = 0; j < 4; ++j) {
    const int t = t0 + j;
    const float xm = (t > 0) ? in[t - 1] : 0.f;
    const float x0 = in[t];
    const float xp = (t < SEQ - 1) ? in[t + 1] : 0.f;
    o[j] = fmaf(w0, xm, fmaf(w1, x0, fmaf(w2, xp, bias)));
  }
  *(float4*)(xc + (size_t)r * SEQ + t0) = make_float4(o[0], o[1], o[2], o[3]);
}

// ---------------- K2: x_proj split-K GEMM (t-tile 64, 512 blocks) ----------
__global__ __launch_bounds__(256) void k2_xproj_sk(
    const float* __restrict__ xc, const float* __restrict__ wp,
    float* __restrict__ part) {
  __shared__ float As[16][100];   // [kk][j], +4 pad
  __shared__ float Bs[16][68];    // [kk][t], +4 pad
  const int tid = threadIdx.x;
  const int tile = blockIdx.x;            // 0..63
  const int ks = blockIdx.y;              // 0..KSL-1
  const int b = tile >> 5;
  const int t0 = (tile & 31) * 64;
  const int kbase = ks * (DIM / KSL);     // 128-wide K slice
  const int tx = tid & 15, ty = tid >> 4;
  float acc[6][4] = {{0.f}};
  for (int k = 0; k < DIM / KSL; k += 16) {
    float a_reg[6];
#pragma unroll
    for (int i = 0; i < 6; ++i) {
      const int ii = tid + 256 * i;
      a_reg[i] = wp[(size_t)(ii >> 4) * DIM + kbase + k + (ii & 15)];
    }
    const int krow = tid >> 4, t4 = (tid & 15) * 4;
    const float4 b_reg = *(const float4*)(
        xc + ((size_t)b * DIM + kbase + k + krow) * SEQ + t0 + t4);
    __syncthreads();
#pragma unroll
    for (int i = 0; i < 6; ++i) {
      const int ii = tid + 256 * i;
      As[ii & 15][ii >> 4] = a_reg[i];
    }
    *(float4*)&Bs[krow][t4] = b_reg;
    __syncthreads();
#pragma unroll
    for (int kk = 0; kk < 16; ++kk) {
      const float4 bA = *(const float4*)&Bs[kk][tx * 4];
#pragma unroll
      for (int i = 0; i < 6; ++i) {
        const float a = As[kk][ty + 16 * i];
        acc[i][0] = fmaf(a, bA.x, acc[i][0]);
        acc[i][1] = fmaf(a, bA.y, acc[i][1]);
        acc[i][2] = fmaf(a, bA.z, acc[i][2]);
        acc[i][3] = fmaf(a, bA.w, acc[i][3]);
      }
    }
    __syncthreads();
  }
#pragma unroll
  for (int i = 0; i < 6; ++i) {
    const int j = ty + 16 * i;
    const size_t o = ((size_t)(ks * BATCH + b) * 96 + j) * SEQ + t0;
    *(float4*)(part + o + tx * 4) =
        make_float4(acc[i][0], acc[i][1], acc[i][2], acc[i][3]);
  }
}

// ---------------- reduce split-K partials -> xdbl ----------------
__global__ __launch_bounds__(256) void k_red(const float* __restrict__ part,
                                             float* __restrict__ xdbl) {
  const size_t PL = (size_t)BATCH * 96 * SEQ;  // 393216
  const size_t i4 = ((size_t)blockIdx.x * 256 + threadIdx.x) * 4;
  float4 s = *(const float4*)(part + i4);
#pragma unroll
  for (int ks = 1; ks < KSL; ++ks) {
    const float4 v = *(const float4*)(part + ks * PL + i4);
    s.x += v.x; s.y += v.y; s.z += v.z; s.w += v.w;
  }
  *(float4*)(xdbl + i4) = s;
}

// ---------------- K3: dt_proj GEMM + softplus (fp32, small) ----------------
__global__ __launch_bounds__(256) void k3_dtproj(
    const float* __restrict__ xdbl, const float* __restrict__ dtw,
    const float* __restrict__ dtb, float* __restrict__ delta) {
  __shared__ float As[16][68];
  __shared__ float Bs[16][68];
  const int tid = threadIdx.x;
  const int b = blockIdx.z;
  const int d0 = blockIdx.y * 64;
  const int t0 = blockIdx.x * 64;
  const int tx = tid & 15, ty = tid >> 4;
  const int lrow = tid >> 2, lcol = (tid & 3) * 4;
  const int bk = tid >> 4, bt4 = (tid & 15) * 4;
  float acc[4][4] = {{0.f}};
  for (int k = 0; k < DTR; k += 16) {
    const float4 av =
        *(const float4*)(dtw + (size_t)(d0 + lrow) * DTR + k + lcol);
    const float4 bv =
        *(const float4*)(xdbl + ((size_t)b * 96 + k + bk) * SEQ + t0 + bt4);
    __syncthreads();
    As[lcol + 0][lrow] = av.x; As[lcol + 1][lrow] = av.y;
    As[lcol + 2][lrow] = av.z; As[lcol + 3][lrow] = av.w;
    Bs[bk][bt4 + 0] = bv.x; Bs[bk][bt4 + 1] = bv.y;
    Bs[bk][bt4 + 2] = bv.z; Bs[bk][bt4 + 3] = bv.w;
    __syncthreads();
#pragma unroll
    for (int kk = 0; kk < 16; ++kk) {
      const float4 a = *(const float4*)&As[kk][ty * 4];
      const float4 b = *(const float4*)&Bs[kk][tx * 4];
      FMA_ROW(0, a.x) FMA_ROW(1, a.y) FMA_ROW(2, a.z) FMA_ROW(3, a.w)
    }
  }
#pragma unroll
  for (int i = 0; i < 4; ++i) {
    const int d = d0 + ty * 4 + i;
    const float bias = dtb[d];
    float4 v;
    v.x = softplus_f(acc[i][0] + bias);
    v.y = softplus_f(acc[i][1] + bias);
    v.z = softplus_f(acc[i][2] + bias);
    v.w = softplus_f(acc[i][3] + bias);
    *(float4*)(delta + ((size_t)b * DIM + d) * SEQ + t0 + tx * 4) = v;
  }
}

// ---------------- fused scan: windowed scan, DPP wave-scan ----------------
__global__ __launch_bounds__(1024) void k_scan_fused(
    const float* __restrict__ delta, const float* __restrict__ u,
    const float* __restrict__ xdbl, const float* __restrict__ A_log,
    const float* __restrict__ Dp, const float* __restrict__ z,
    float* __restrict__ y) {
  __shared__ float red[2][NST][2][260];   // ~66.5 KB, double-buffered
  const int tid = threadIdx.x;
  const int wv = tid >> 6;             // 0..15 == n
  const int lane = tid & 63;
  const int idx = blockIdx.x;          // b*DIM + d
  const int b = idx >> 10, d = idx & (DIM - 1);
  const float A = -expf(A_log[d * NST + wv]);
  const float Dprm = Dp[d];
  const float* drow = delta + (size_t)idx * SEQ;
  const float* urow = u + (size_t)idx * SEQ;
  const float* Brow = xdbl + ((size_t)b * 96 + DTR + wv) * SEQ;
  const float* Crow = xdbl + ((size_t)b * 96 + DTR + NST + wv) * SEQ;
  const float* zrow = z + (size_t)idx * SEQ;
  float* yrow = y + (size_t)idx * SEQ;
  float s_c = 0.f;                     // running state carry for (b,d,n)
  const int tl = lane * 8;
  const int tl2 = lane * 4;

  // preload window 0 inputs (d,u,B); C is loaded per-window below
  float4 dA = *(const float4*)(drow + tl);
  float4 dB = *(const float4*)(drow + tl + 4);
  float4 uA = *(const float4*)(urow + tl);
  float4 uB = *(const float4*)(urow + tl + 4);
  float4 bA = *(const float4*)(Brow + tl);
  float4 bB = *(const float4*)(Brow + tl + 4);
  // reduce-slot u/z for window 0 (waves 0..7 only; wave-uniform branch)
  float uRc = 0.f, zRc = 0.f;
  if (tid < 512) { uRc = urow[tid]; zRc = zrow[tid]; }

  for (int w = 0; w < SEQ / 512; ++w) {
    const int t0 = w * 512;
    // issue C loads for THIS window early (consumed only at reconstruct)
    const float4 cA = *(const float4*)(Crow + t0 + tl);
    const float4 cB = *(const float4*)(Crow + t0 + tl + 4);
    // prefetch next window's reduce-slot u/z
    float uRn = 0.f, zRn = 0.f;
    if (w + 1 < SEQ / 512 && tid < 512) {
      uRn = urow[t0 + 512 + tid];
      zRn = zrow[t0 + 512 + tid];
    }
    // local (a,b) compose + inclusive prefixes within the lane's 8 elems
    float p[8], q[8];
    {
      const float dls[8] = {dA.x, dA.y, dA.z, dA.w, dB.x, dB.y, dB.z, dB.w};
      const float us[8]  = {uA.x, uA.y, uA.z, uA.w, uB.x, uB.y, uB.z, uB.w};
      const float Bb[8]  = {bA.x, bA.y, bA.z, bA.w, bB.x, bB.y, bB.z, bB.w};
      p[0] = __expf(dls[0] * A);
      q[0] = dls[0] * us[0] * Bb[0];
#pragma unroll
      for (int i = 1; i < 8; ++i) {
        const float a = __expf(dls[i] * A);
        const float bq = dls[i] * us[i] * Bb[i];
        p[i] = a * p[i - 1];
        q[i] = fmaf(a, q[i - 1], bq);
      }
    }
    // prefetch next window's d/u/B now that the current ones are consumed
    if (w + 1 < SEQ / 512) {
      const int tn = t0 + 512 + tl;
      dA = *(const float4*)(drow + tn);
      dB = *(const float4*)(drow + tn + 4);
      uA = *(const float4*)(urow + tn);
      uB = *(const float4*)(urow + tn + 4);
      bA = *(const float4*)(Brow + tn);
      bB = *(const float4*)(Brow + tn + 4);
    }
    // wave-wide inclusive scan of lane aggregates via DPP (VALU pipe)
    float ia = p[7], ib = q[7];
    {
      float oa, ob;
      oa = dpp_mov<0x111, 0xf>(1.f, ia);  // row_shr:1
      ob = dpp_mov<0x111, 0xf>(0.f, ib);
      ib = fmaf(ia, ob, ib); ia *= oa;
      oa = dpp_mov<0x112, 0xf>(1.f, ia);  // row_shr:2
      ob = dpp_mov<0x112, 0xf>(0.f, ib);
      ib = fmaf(ia, ob, ib); ia *= oa;
      oa = dpp_mov<0x114, 0xf>(1.f, ia);  // row_shr:4
      ob = dpp_mov<0x114, 0xf>(0.f, ib);
      ib = fmaf(ia, ob, ib); ia *= oa;
      oa = dpp_mov<0x118, 0xf>(1.f, ia);  // row_shr:8
      ob = dpp_mov<0x118, 0xf>(0.f, ib);
      ib = fmaf(ia, ob, ib); ia *= oa;
      oa = dpp_mov<0x142, 0xa>(1.f, ia);  // row_bcast15 -> rows 1,3
      ob = dpp_mov<0x142, 0xa>(0.f, ib);
      ib = fmaf(ia, ob, ib); ia *= oa;
      oa = dpp_mov<0x143, 0xc>(1.f, ia);  // row_bcast31 -> rows 2,3
      ob = dpp_mov<0x143, 0xc>(0.f, ib);
      ib = fmaf(ia, ob, ib); ia *= oa;
    }
    // window aggregate (lane 63) -> carry update
    const float Wa = __shfl(ia, 63, 64);
    const float Wb = __shfl(ib, 63, 64);
    // exclusive prefix for this lane
    float ea = __shfl_up(ia, 1, 64);
    float eb = __shfl_up(ib, 1, 64);
    if (lane == 0) { ea = 1.f; eb = 0.f; }
    const float S = fmaf(ea, s_c, eb);   // state entering lane's segment
    s_c = fmaf(Wa, s_c, Wb);
    // reconstruct per-element states, y-partials
    float4 y0, y1;
    y0.x = fmaf(p[0], S, q[0]) * cA.x;
    y0.y = fmaf(p[1], S, q[1]) * cA.y;
    y0.z = fmaf(p[2], S, q[2]) * cA.z;
    y0.w = fmaf(p[3], S, q[3]) * cA.w;
    y1.x = fmaf(p[4], S, q[4]) * cB.x;
    y1.y = fmaf(p[5], S, q[5]) * cB.y;
    y1.z = fmaf(p[6], S, q[6]) * cB.z;
    y1.w = fmaf(p[7], S, q[7]) * cB.w;
    // lane-contiguous sub-row writes: t=8l+e -> sub=(e>>2), pos=4l+(e&3)
    *(float4*)&red[w & 1][wv][0][tl2] = y0;
    *(float4*)&red[w & 1][wv][1][tl2] = y1;
    __syncthreads();
    if (tid < 512) {
      const int sub = (tid >> 2) & 1;
      const int pos = ((tid >> 3) << 2) | (tid & 3);
      float sum = 0.f;
#pragma unroll
      for (int nn = 0; nn < NST; ++nn) sum += red[w & 1][nn][sub][pos];
      sum = fmaf(uRc, Dprm, sum);
      const float sg = __builtin_amdgcn_rcpf(1.f + __expf(-zRc));
      yrow[t0 + tid] = sum * zRc * sg;
    }
    uRc = uRn;
    zRc = zRn;
  }
}

// ---------------- transpose + split: y(b,d,t) -> gh/gl (b,t,d) f16 ----------
__global__ __launch_bounds__(256) void k_gt(
    const float* __restrict__ y, _Float16* __restrict__ gh,
    _Float16* __restrict__ gl) {
  __shared__ _Float16 th[64][68];  // [d_local][t_local]
  __shared__ _Float16 tl[64][68];
  const int ti = threadIdx.x;
  const int t0 = blockIdx.x * 64;
  const int d0 = blockIdx.y * 64;
  const int b = blockIdx.z;
  const int c4 = (ti & 15) * 4;
#pragma unroll
  for (int rr = 0; rr < 4; ++rr) {
    const int dl_ = (ti >> 4) + 16 * rr;
    const size_t base = ((size_t)b * DIM + d0 + dl_) * SEQ + t0 + c4;
    const float4 yv = *(const float4*)(y + base);
    const float gy[4] = {yv.x, yv.y, yv.z, yv.w};
#pragma unroll
    for (int k = 0; k < 4; ++k) {
      const _Float16 h = (_Float16)gy[k];
      th[dl_][c4 + k] = h;
      tl[dl_][c4 + k] = (_Float16)(gy[k] - (float)h);
    }
  }
  __syncthreads();
#pragma unroll
  for (int rr = 0; rr < 2; ++rr) {
    const int chunk = ti + 256 * rr;
    const int tloc = chunk >> 3;
    const int dchunk = (chunk & 7) * 8;
    f16x8 hv, lv;
#pragma unroll
    for (int j = 0; j < 8; ++j) {
      hv[j] = th[dchunk + j][tloc];
      lv[j] = tl[dchunk + j][tloc];
    }
    const size_t o = ((size_t)b * SEQ + t0 + tloc) * DIM + d0 + dchunk;
    *(f16x8*)(gh + o) = hv;
    *(f16x8*)(gl + o) = lv;
  }
}

extern "C" void kernel_launch(void* const* d_in, const int* in_sizes, int n_in,
                              void* d_out, int out_size, void* d_ws,
                              size_t ws_size, hipStream_t stream) {
  const float* x          = (const float*)d_in[0];
  const float* in_proj_w  = (const float*)d_in[1];
  const float* conv_w     = (const float*)d_in[2];
  const float* conv_b     = (const float*)d_in[3];
  const float* A_log      = (const float*)d_in[4];
  const float* D_param    = (const float*)d_in[5];
  const float* x_proj_w   = (const float*)d_in[6];
  const float* dt_proj_w  = (const float*)d_in[7];
  const float* dt_proj_b  = (const float*)d_in[8];
  const float* out_proj_w = (const float*)d_in[9];
  float* out = (float*)d_out;
  float* ws = (float*)d_ws;

  const size_t PLANE = (size_t)BATCH * SEQ * DIM;  // 4M floats (16 MB)
  float* xcraw = ws;               // plane0: xcraw -> delta -> gh/gl
  float* delta = ws;
  _Float16* gh = (_Float16*)ws;
  _Float16* gl = (_Float16*)ws + PLANE;
  float* xc    = ws + PLANE;       // (b,d,t) post-conv
  float* zbuf  = ws + 2 * PLANE;   // (b,dz,t) channel-major
  float* part  = ws + 3 * PLANE;   // plane3: part -> ybuf
  float* ybuf  = ws + 3 * PLANE;
  float* xdbl  = ws + 4 * PLANE;   // (b,96,t) 393216 floats
  _Float16* wih = (_Float16*)(ws + 4 * PLANE + 1572864);
  _Float16* wil = wih + (size_t)2 * DIM * DIM;
  _Float16* woh = wil + (size_t)2 * DIM * DIM;
  _Float16* wol = woh + (size_t)DIM * DIM;

  k_cvt2<<<dim3(1536), 256, 0, stream>>>(in_proj_w, wih, wil,
                                         out_proj_w, woh, wol);

  kgemm_f16x3<1><<<dim3(32, 16), 256, 0, stream>>>(wih, wil, nullptr, nullptr,
                                                   x, xcraw, zbuf);
  k_conv<<<dim3((BATCH * DIM * SEQ / 4) / 256), 256, 0, stream>>>(
      xcraw, conv_w, conv_b, xc);
  k2_xproj_sk<<<dim3(64, KSL), 256, 0, stream>>>(xc, x_proj_w, part);
  k_red<<<dim3(384), 256, 0, stream>>>(part, xdbl);
  k3_dtproj<<<dim3(SEQ / 64, DIM / 64, BATCH), 256, 0, stream>>>(
      xdbl, dt_proj_w, dt_proj_b, delta);
  k_scan_fused<<<dim3(BATCH * DIM), 1024, 0, stream>>>(
      delta, xc, xdbl, A_log, D_param, zbuf, ybuf);
  k_gt<<<dim3(SEQ / 64, DIM / 64, BATCH), 256, 0, stream>>>(ybuf, gh, gl);
  kgemm_f16x3<0><<<dim3(8, 32), 256, 0, stream>>>(gh, gl, woh, wol, nullptr,
                                                  out, nullptr);
}

// Round 9
// 275.742 us; speedup vs baseline: 1.0651x; 1.0651x over previous
//
#include <hip/hip_runtime.h>
#include <math.h>

#define BATCH 2
#define SEQ   2048
#define DIM   1024
#define NST   16
#define DTR   64
#define KSL   8                     // split-K slices for x_proj

typedef _Float16 f16x8 __attribute__((ext_vector_type(8)));
typedef float f32x4 __attribute__((ext_vector_type(4)));

__device__ __forceinline__ float softplus_f(float v) {
  return fmaxf(v, 0.f) + log1pf(expf(-fabsf(v)));
}

__device__ __forceinline__ void gl_lds16(const _Float16* g, _Float16* l) {
  __builtin_amdgcn_global_load_lds(
      (const __attribute__((address_space(1))) void*)g,
      (__attribute__((address_space(3))) void*)l, 16, 0, 0);
}

// DPP move with explicit fallback (old) for invalid source lanes.
template <int CTRL, int RMASK>
__device__ __forceinline__ float dpp_mov(float oldv, float src) {
  return __int_as_float(__builtin_amdgcn_update_dpp(
      __float_as_int(oldv), __float_as_int(src), CTRL, RMASK, 0xf, false));
}

#define FMA_ROW(i, av)                                        \
  acc[i][0] = fmaf(av, b.x, acc[i][0]);                       \
  acc[i][1] = fmaf(av, b.y, acc[i][1]);                       \
  acc[i][2] = fmaf(av, b.z, acc[i][2]);                       \
  acc[i][3] = fmaf(av, b.w, acc[i][3]);

// ---------------- split fp32 -> hi/lo f16 planes (3 arrays, 1 launch) -------
__global__ __launch_bounds__(256) void k_cvt3(
    const float* __restrict__ in0, _Float16* __restrict__ hi0,
    _Float16* __restrict__ lo0,                       // x: 2048 blocks
    const float* __restrict__ in1, _Float16* __restrict__ hi1,
    _Float16* __restrict__ lo1,                       // in_proj_w: 1024 blocks
    const float* __restrict__ in2, _Float16* __restrict__ hi2,
    _Float16* __restrict__ lo2) {                     // out_proj_w: 512 blocks
  int bb = blockIdx.x;
  const float* in;
  _Float16 *hi, *lo;
  if (bb < 2048) {
    in = in0; hi = hi0; lo = lo0;
  } else if (bb < 3072) {
    in = in1; hi = hi1; lo = lo1; bb -= 2048;
  } else {
    in = in2; hi = hi2; lo = lo2; bb -= 3072;
  }
  const int i = (bb * 256 + threadIdx.x) * 8;
  const float4 a = *(const float4*)(in + i);
  const float4 b = *(const float4*)(in + i + 4);
  const float v[8] = {a.x, a.y, a.z, a.w, b.x, b.y, b.z, b.w};
  f16x8 h, l;
#pragma unroll
  for (int j = 0; j < 8; ++j) {
    const _Float16 hh = (_Float16)v[j];
    h[j] = hh;
    l[j] = (_Float16)(v[j] - (float)hh);
  }
  *(f16x8*)(hi + i) = h;
  *(f16x8*)(lo + i) = l;
}

// ---------------- f16x3 NT GEMM: D[m][n] = sum_k A[m,k]*B[n,k], K=LD=1024 ----
// 2-phase ping-pong: STAGE(k+1) issued before compute(k); one barrier/K-step.
// LDS chunk swizzle c ^= (row>>1)&3 applied on BOTH the global source (staging)
// and the ds_read address -> conflict-free b128 fragment reads. (Proven r6
// config; the r7/r8 fused-cvt variants were net-negative and are reverted.)
template <int EPI>
__global__ __launch_bounds__(256) void kgemm_f16x3(
    const _Float16* __restrict__ Ah, const _Float16* __restrict__ Al,
    const _Float16* __restrict__ Bh, const _Float16* __restrict__ Bl,
    float* __restrict__ out0, float* __restrict__ out1) {
  __shared__ _Float16 sm[32768];  // 64 KB: 2 buffers x (Ah|Al|Bh|Bl) 128x32
  const int tid = threadIdx.x;
  const int wid = tid >> 6, lane = tid & 63;
  const int wm = wid >> 1, wn = wid & 1;
  const int m0 = blockIdx.y * 128;
  const int n0 = blockIdx.x * 128;

  const int r0 = wid * 32;
  const int srow = lane >> 2;
  // staging source: chunk (lane&3) ^ swz, swz = (row>>1)&3 = (lane>>3)&3
  const int skqs = ((lane & 3) ^ ((lane >> 3) & 3)) * 8;
  const _Float16* gAh = Ah + (size_t)(m0 + r0 + srow) * 1024 + skqs;
  const _Float16* gAl = Al + (size_t)(m0 + r0 + srow) * 1024 + skqs;
  const _Float16* gBh = Bh + (size_t)(n0 + r0 + srow) * 1024 + skqs;
  const _Float16* gBl = Bl + (size_t)(n0 + r0 + srow) * 1024 + skqs;

  const int fr = lane & 15;
  // fragment read: desired chunk (lane>>4), stored at chunk^((row>>1)&3)
  const int fks = (((lane >> 4) ^ ((fr >> 1) & 3))) * 8;

  f32x4 acc[4][4];
#pragma unroll
  for (int i = 0; i < 4; ++i)
#pragma unroll
    for (int j = 0; j < 4; ++j) acc[i][j] = (f32x4)(0.f);

  auto STAGE = [&](int buf, int k0) {
    _Float16* base = sm + buf * 16384;
    _Float16* lA = base + r0 * 32;   // this wave's 32 rows of each tile
    gl_lds16(gAh + k0, lA);
    gl_lds16(gAh + k0 + 16 * 1024, lA + 512);
    gl_lds16(gAl + k0, lA + 4096);
    gl_lds16(gAl + k0 + 16 * 1024, lA + 4096 + 512);
    gl_lds16(gBh + k0, lA + 8192);
    gl_lds16(gBh + k0 + 16 * 1024, lA + 8192 + 512);
    gl_lds16(gBl + k0, lA + 12288);
    gl_lds16(gBl + k0 + 16 * 1024, lA + 12288 + 512);
  };

  STAGE(0, 0);
  int cur = 0;
  for (int k0 = 0; k0 < 1024; k0 += 32) {
    __syncthreads();   // drains vmcnt: buf[cur] ready; buf[cur^1] free
    if (k0 + 32 < 1024) STAGE(cur ^ 1, k0 + 32);
    const _Float16* base = sm + cur * 16384;

    f16x8 ah[4], alo[4], bh[4], blo[4];
#pragma unroll
    for (int i = 0; i < 4; ++i) {
      const int ao = (wm * 64 + i * 16 + fr) * 32 + fks;
      const int bo = (wn * 64 + i * 16 + fr) * 32 + fks;
      ah[i]  = *(const f16x8*)(base + ao);
      alo[i] = *(const f16x8*)(base + 4096 + ao);
      bh[i]  = *(const f16x8*)(base + 8192 + bo);
      blo[i] = *(const f16x8*)(base + 12288 + bo);
    }
#pragma unroll
    for (int i = 0; i < 4; ++i)
#pragma unroll
      for (int j = 0; j < 4; ++j) {
        acc[i][j] = __builtin_amdgcn_mfma_f32_16x16x32_f16(ah[i], bh[j],
                                                           acc[i][j], 0, 0, 0);
        acc[i][j] = __builtin_amdgcn_mfma_f32_16x16x32_f16(ah[i], blo[j],
                                                           acc[i][j], 0, 0, 0);
        acc[i][j] = __builtin_amdgcn_mfma_f32_16x16x32_f16(alo[i], bh[j],
                                                           acc[i][j], 0, 0, 0);
      }
    cur ^= 1;
  }

  const int lr4 = (lane >> 4) * 4, lc = lane & 15;
#pragma unroll
  for (int i = 0; i < 4; ++i) {
#pragma unroll
    for (int j = 0; j < 4; ++j) {
      const int ar = m0 + wm * 64 + i * 16 + lr4;
      const int bc = n0 + wn * 64 + j * 16 + lc;
#pragma unroll
      for (int r = 0; r < 4; ++r) {
        const float v = acc[i][j][r];
        if (EPI == 0) {
          out0[(size_t)(ar + r) * 1024 + bc] = v;
        } else {
          const int bb = bc >> 11, tt = bc & 2047;
          if (ar < 1024) {
            out0[((size_t)bb * 1024 + ar + r) * 2048 + tt] = v;
          } else {
            out1[((size_t)bb * 1024 + (ar + r - 1024)) * 2048 + tt] = v;
          }
        }
      }
    }
  }
}

// ---------------- K2: x_proj split-K GEMM + fused depthwise conv -----------
// k2's B-tile access covers each (b,d,t) of the conv output exactly once
// (ks slices partition d; tiles partition (b,t)), so the k=3 depthwise conv
// is computed inline from xcraw, written to xc (scan's u input), and fed
// straight into Bs. Deletes the standalone k_conv kernel.
__global__ __launch_bounds__(256) void k2_xproj_conv(
    const float* __restrict__ xcraw, const float* __restrict__ cw,
    const float* __restrict__ cb, float* __restrict__ xc,
    const float* __restrict__ wp, float* __restrict__ part) {
  __shared__ float As[16][100];   // [kk][j], +4 pad
  __shared__ float Bs[16][68];    // [kk][t], +4 pad
  const int tid = threadIdx.x;
  const int tile = blockIdx.x;            // 0..63
  const int ks = blockIdx.y;              // 0..KSL-1
  const int b = tile >> 5;
  const int t0 = (tile & 31) * 64;
  const int kbase = ks * (DIM / KSL);     // 128-wide K slice
  const int tx = tid & 15, ty = tid >> 4;
  const int krow = tid >> 4, t4v = (tid & 15) * 4;
  float acc[6][4] = {{0.f}};
  for (int k = 0; k < DIM / KSL; k += 16) {
    float a_reg[6];
#pragma unroll
    for (int i = 0; i < 6; ++i) {
      const int ii = tid + 256 * i;
      a_reg[i] = wp[(size_t)(ii >> 4) * DIM + kbase + k + (ii & 15)];
    }
    // fused conv: load xcraw neighborhood, conv, write xc, use as B
    const int d = kbase + k + krow;
    const float w0 = cw[d * 3 + 0], w1 = cw[d * 3 + 1], w2 = cw[d * 3 + 2];
    const float bias = cb[d];
    const size_t base = ((size_t)b * DIM + d) * SEQ + t0 + t4v;
    const int tg = t0 + t4v;
    const float4 xv = *(const float4*)(xcraw + base);
    const float xm = (tg > 0) ? xcraw[base - 1] : 0.f;
    const float xp = (tg + 4 < SEQ) ? xcraw[base + 4] : 0.f;
    float4 b_reg;
    b_reg.x = fmaf(w0, xm,   fmaf(w1, xv.x, fmaf(w2, xv.y, bias)));
    b_reg.y = fmaf(w0, xv.x, fmaf(w1, xv.y, fmaf(w2, xv.z, bias)));
    b_reg.z = fmaf(w0, xv.y, fmaf(w1, xv.z, fmaf(w2, xv.w, bias)));
    b_reg.w = fmaf(w0, xv.z, fmaf(w1, xv.w, fmaf(w2, xp,   bias)));
    *(float4*)(xc + base) = b_reg;
    __syncthreads();
#pragma unroll
    for (int i = 0; i < 6; ++i) {
      const int ii = tid + 256 * i;
      As[ii & 15][ii >> 4] = a_reg[i];
    }
    *(float4*)&Bs[krow][t4v] = b_reg;
    __syncthreads();
#pragma unroll
    for (int kk = 0; kk < 16; ++kk) {
      const float4 bA = *(const float4*)&Bs[kk][tx * 4];
#pragma unroll
      for (int i = 0; i < 6; ++i) {
        const float a = As[kk][ty + 16 * i];
        acc[i][0] = fmaf(a, bA.x, acc[i][0]);
        acc[i][1] = fmaf(a, bA.y, acc[i][1]);
        acc[i][2] = fmaf(a, bA.z, acc[i][2]);
        acc[i][3] = fmaf(a, bA.w, acc[i][3]);
      }
    }
    __syncthreads();
  }
#pragma unroll
  for (int i = 0; i < 6; ++i) {
    const int j = ty + 16 * i;
    const size_t o = ((size_t)(ks * BATCH + b) * 96 + j) * SEQ + t0;
    *(float4*)(part + o + tx * 4) =
        make_float4(acc[i][0], acc[i][1], acc[i][2], acc[i][3]);
  }
}

// ---------------- reduce split-K partials -> xdbl ----------------
__global__ __launch_bounds__(256) void k_red(const float* __restrict__ part,
                                             float* __restrict__ xdbl) {
  const size_t PL = (size_t)BATCH * 96 * SEQ;  // 393216
  const size_t i4 = ((size_t)blockIdx.x * 256 + threadIdx.x) * 4;
  float4 s = *(const float4*)(part + i4);
#pragma unroll
  for (int ks = 1; ks < KSL; ++ks) {
    const float4 v = *(const float4*)(part + ks * PL + i4);
    s.x += v.x; s.y += v.y; s.z += v.z; s.w += v.w;
  }
  *(float4*)(xdbl + i4) = s;
}

// ---------------- K3: dt_proj GEMM + softplus (fp32, small) ----------------
__global__ __launch_bounds__(256) void k3_dtproj(
    const float* __restrict__ xdbl, const float* __restrict__ dtw,
    const float* __restrict__ dtb, float* __restrict__ delta) {
  __shared__ float As[16][68];
  __shared__ float Bs[16][68];
  const int tid = threadIdx.x;
  const int b = blockIdx.z;
  const int d0 = blockIdx.y * 64;
  const int t0 = blockIdx.x * 64;
  const int tx = tid & 15, ty = tid >> 4;
  const int lrow = tid >> 2, lcol = (tid & 3) * 4;
  const int bk = tid >> 4, bt4 = (tid & 15) * 4;
  float acc[4][4] = {{0.f}};
  for (int k = 0; k < DTR; k += 16) {
    const float4 av =
        *(const float4*)(dtw + (size_t)(d0 + lrow) * DTR + k + lcol);
    const float4 bv =
        *(const float4*)(xdbl + ((size_t)b * 96 + k + bk) * SEQ + t0 + bt4);
    __syncthreads();
    As[lcol + 0][lrow] = av.x; As[lcol + 1][lrow] = av.y;
    As[lcol + 2][lrow] = av.z; As[lcol + 3][lrow] = av.w;
    Bs[bk][bt4 + 0] = bv.x; Bs[bk][bt4 + 1] = bv.y;
    Bs[bk][bt4 + 2] = bv.z; Bs[bk][bt4 + 3] = bv.w;
    __syncthreads();
#pragma unroll
    for (int kk = 0; kk < 16; ++kk) {
      const float4 a = *(const float4*)&As[kk][ty * 4];
      const float4 b = *(const float4*)&Bs[kk][tx * 4];
      FMA_ROW(0, a.x) FMA_ROW(1, a.y) FMA_ROW(2, a.z) FMA_ROW(3, a.w)
    }
  }
#pragma unroll
  for (int i = 0; i < 4; ++i) {
    const int d = d0 + ty * 4 + i;
    const float bias = dtb[d];
    float4 v;
    v.x = softplus_f(acc[i][0] + bias);
    v.y = softplus_f(acc[i][1] + bias);
    v.z = softplus_f(acc[i][2] + bias);
    v.w = softplus_f(acc[i][3] + bias);
    *(float4*)(delta + ((size_t)b * DIM + d) * SEQ + t0 + tx * 4) = v;
  }
}

// ---------------- fused scan: windowed scan, DPP wave-scan ----------------
__global__ __launch_bounds__(1024) void k_scan_fused(
    const float* __restrict__ delta, const float* __restrict__ u,
    const float* __restrict__ xdbl, const float* __restrict__ A_log,
    const float* __restrict__ Dp, const float* __restrict__ z,
    float* __restrict__ y) {
  __shared__ float red[2][NST][2][260];   // ~66.5 KB, double-buffered
  const int tid = threadIdx.x;
  const int wv = tid >> 6;             // 0..15 == n
  const int lane = tid & 63;
  const int idx = blockIdx.x;          // b*DIM + d
  const int b = idx >> 10, d = idx & (DIM - 1);
  const float A = -expf(A_log[d * NST + wv]);
  const float Dprm = Dp[d];
  const float* drow = delta + (size_t)idx * SEQ;
  const float* urow = u + (size_t)idx * SEQ;
  const float* Brow = xdbl + ((size_t)b * 96 + DTR + wv) * SEQ;
  const float* Crow = xdbl + ((size_t)b * 96 + DTR + NST + wv) * SEQ;
  const float* zrow = z + (size_t)idx * SEQ;
  float* yrow = y + (size_t)idx * SEQ;
  float s_c = 0.f;                     // running state carry for (b,d,n)
  const int tl = lane * 8;
  const int tl2 = lane * 4;

  // preload window 0 inputs (d,u,B); C is loaded per-window below
  float4 dA = *(const float4*)(drow + tl);
  float4 dB = *(const float4*)(drow + tl + 4);
  float4 uA = *(const float4*)(urow + tl);
  float4 uB = *(const float4*)(urow + tl + 4);
  float4 bA = *(const float4*)(Brow + tl);
  float4 bB = *(const float4*)(Brow + tl + 4);
  // reduce-slot u/z for window 0 (waves 0..7 only; wave-uniform branch)
  float uRc = 0.f, zRc = 0.f;
  if (tid < 512) { uRc = urow[tid]; zRc = zrow[tid]; }

  for (int w = 0; w < SEQ / 512; ++w) {
    const int t0 = w * 512;
    // issue C loads for THIS window early (consumed only at reconstruct)
    const float4 cA = *(const float4*)(Crow + t0 + tl);
    const float4 cB = *(const float4*)(Crow + t0 + tl + 4);
    // prefetch next window's reduce-slot u/z
    float uRn = 0.f, zRn = 0.f;
    if (w + 1 < SEQ / 512 && tid < 512) {
      uRn = urow[t0 + 512 + tid];
      zRn = zrow[t0 + 512 + tid];
    }
    // local (a,b) compose + inclusive prefixes within the lane's 8 elems
    float p[8], q[8];
    {
      const float dls[8] = {dA.x, dA.y, dA.z, dA.w, dB.x, dB.y, dB.z, dB.w};
      const float us[8]  = {uA.x, uA.y, uA.z, uA.w, uB.x, uB.y, uB.z, uB.w};
      const float Bb[8]  = {bA.x, bA.y, bA.z, bA.w, bB.x, bB.y, bB.z, bB.w};
      p[0] = __expf(dls[0] * A);
      q[0] = dls[0] * us[0] * Bb[0];
#pragma unroll
      for (int i = 1; i < 8; ++i) {
        const float a = __expf(dls[i] * A);
        const float bq = dls[i] * us[i] * Bb[i];
        p[i] = a * p[i - 1];
        q[i] = fmaf(a, q[i - 1], bq);
      }
    }
    // prefetch next window's d/u/B now that the current ones are consumed
    if (w + 1 < SEQ / 512) {
      const int tn = t0 + 512 + tl;
      dA = *(const float4*)(drow + tn);
      dB = *(const float4*)(drow + tn + 4);
      uA = *(const float4*)(urow + tn);
      uB = *(const float4*)(urow + tn + 4);
      bA = *(const float4*)(Brow + tn);
      bB = *(const float4*)(Brow + tn + 4);
    }
    // wave-wide inclusive scan of lane aggregates via DPP (VALU pipe)
    float ia = p[7], ib = q[7];
    {
      float oa, ob;
      oa = dpp_mov<0x111, 0xf>(1.f, ia);  // row_shr:1
      ob = dpp_mov<0x111, 0xf>(0.f, ib);
      ib = fmaf(ia, ob, ib); ia *= oa;
      oa = dpp_mov<0x112, 0xf>(1.f, ia);  // row_shr:2
      ob = dpp_mov<0x112, 0xf>(0.f, ib);
      ib = fmaf(ia, ob, ib); ia *= oa;
      oa = dpp_mov<0x114, 0xf>(1.f, ia);  // row_shr:4
      ob = dpp_mov<0x114, 0xf>(0.f, ib);
      ib = fmaf(ia, ob, ib); ia *= oa;
      oa = dpp_mov<0x118, 0xf>(1.f, ia);  // row_shr:8
      ob = dpp_mov<0x118, 0xf>(0.f, ib);
      ib = fmaf(ia, ob, ib); ia *= oa;
      oa = dpp_mov<0x142, 0xa>(1.f, ia);  // row_bcast15 -> rows 1,3
      ob = dpp_mov<0x142, 0xa>(0.f, ib);
      ib = fmaf(ia, ob, ib); ia *= oa;
      oa = dpp_mov<0x143, 0xc>(1.f, ia);  // row_bcast31 -> rows 2,3
      ob = dpp_mov<0x143, 0xc>(0.f, ib);
      ib = fmaf(ia, ob, ib); ia *= oa;
    }
    // window aggregate (lane 63) -> carry update
    const float Wa = __shfl(ia, 63, 64);
    const float Wb = __shfl(ib, 63, 64);
    // exclusive prefix for this lane
    float ea = __shfl_up(ia, 1, 64);
    float eb = __shfl_up(ib, 1, 64);
    if (lane == 0) { ea = 1.f; eb = 0.f; }
    const float S = fmaf(ea, s_c, eb);   // state entering lane's segment
    s_c = fmaf(Wa, s_c, Wb);
    // reconstruct per-element states, y-partials
    float4 y0, y1;
    y0.x = fmaf(p[0], S, q[0]) * cA.x;
    y0.y = fmaf(p[1], S, q[1]) * cA.y;
    y0.z = fmaf(p[2], S, q[2]) * cA.z;
    y0.w = fmaf(p[3], S, q[3]) * cA.w;
    y1.x = fmaf(p[4], S, q[4]) * cB.x;
    y1.y = fmaf(p[5], S, q[5]) * cB.y;
    y1.z = fmaf(p[6], S, q[6]) * cB.z;
    y1.w = fmaf(p[7], S, q[7]) * cB.w;
    // lane-contiguous sub-row writes: t=8l+e -> sub=(e>>2), pos=4l+(e&3)
    *(float4*)&red[w & 1][wv][0][tl2] = y0;
    *(float4*)&red[w & 1][wv][1][tl2] = y1;
    __syncthreads();
    if (tid < 512) {
      const int sub = (tid >> 2) & 1;
      const int pos = ((tid >> 3) << 2) | (tid & 3);
      float sum = 0.f;
#pragma unroll
      for (int nn = 0; nn < NST; ++nn) sum += red[w & 1][nn][sub][pos];
      sum = fmaf(uRc, Dprm, sum);
      const float sg = __builtin_amdgcn_rcpf(1.f + __expf(-zRc));
      yrow[t0 + tid] = sum * zRc * sg;
    }
    uRc = uRn;
    zRc = zRn;
  }
}

// ---------------- transpose + split: y(b,d,t) -> gh/gl (b,t,d) f16 ----------
__global__ __launch_bounds__(256) void k_gt(
    const float* __restrict__ y, _Float16* __restrict__ gh,
    _Float16* __restrict__ gl) {
  __shared__ _Float16 th[64][68];  // [d_local][t_local]
  __shared__ _Float16 tl[64][68];
  const int ti = threadIdx.x;
  const int t0 = blockIdx.x * 64;
  const int d0 = blockIdx.y * 64;
  const int b = blockIdx.z;
  const int c4 = (ti & 15) * 4;
#pragma unroll
  for (int rr = 0; rr < 4; ++rr) {
    const int dl_ = (ti >> 4) + 16 * rr;
    const size_t base = ((size_t)b * DIM + d0 + dl_) * SEQ + t0 + c4;
    const float4 yv = *(const float4*)(y + base);
    const float gy[4] = {yv.x, yv.y, yv.z, yv.w};
#pragma unroll
    for (int k = 0; k < 4; ++k) {
      const _Float16 h = (_Float16)gy[k];
      th[dl_][c4 + k] = h;
      tl[dl_][c4 + k] = (_Float16)(gy[k] - (float)h);
    }
  }
  __syncthreads();
#pragma unroll
  for (int rr = 0; rr < 2; ++rr) {
    const int chunk = ti + 256 * rr;
    const int tloc = chunk >> 3;
    const int dchunk = (chunk & 7) * 8;
    f16x8 hv, lv;
#pragma unroll
    for (int j = 0; j < 8; ++j) {
      hv[j] = th[dchunk + j][tloc];
      lv[j] = tl[dchunk + j][tloc];
    }
    const size_t o = ((size_t)b * SEQ + t0 + tloc) * DIM + d0 + dchunk;
    *(f16x8*)(gh + o) = hv;
    *(f16x8*)(gl + o) = lv;
  }
}

extern "C" void kernel_launch(void* const* d_in, const int* in_sizes, int n_in,
                              void* d_out, int out_size, void* d_ws,
                              size_t ws_size, hipStream_t stream) {
  const float* x          = (const float*)d_in[0];
  const float* in_proj_w  = (const float*)d_in[1];
  const float* conv_w     = (const float*)d_in[2];
  const float* conv_b     = (const float*)d_in[3];
  const float* A_log      = (const float*)d_in[4];
  const float* D_param    = (const float*)d_in[5];
  const float* x_proj_w   = (const float*)d_in[6];
  const float* dt_proj_w  = (const float*)d_in[7];
  const float* dt_proj_b  = (const float*)d_in[8];
  const float* out_proj_w = (const float*)d_in[9];
  float* out = (float*)d_out;
  float* ws = (float*)d_ws;

  const size_t PLANE = (size_t)BATCH * SEQ * DIM;  // 4M floats (16 MB)
  float* xcraw = ws;               // plane0: xcraw -> delta -> gh/gl
  float* delta = ws;
  _Float16* gh = (_Float16*)ws;
  _Float16* gl = (_Float16*)ws + PLANE;
  float* xc    = ws + PLANE;       // (b,d,t) post-conv
  float* zbuf  = ws + 2 * PLANE;   // (b,dz,t) channel-major
  _Float16* xh = (_Float16*)(ws + 3 * PLANE);  // plane3: xh/xl -> part -> ybuf
  _Float16* xl = xh + PLANE;
  float* part  = ws + 3 * PLANE;
  float* ybuf  = ws + 3 * PLANE;
  float* xdbl  = ws + 4 * PLANE;   // (b,96,t) 393216 floats
  _Float16* wih = (_Float16*)(ws + 4 * PLANE + 1572864);
  _Float16* wil = wih + (size_t)2 * DIM * DIM;
  _Float16* woh = wil + (size_t)2 * DIM * DIM;
  _Float16* wol = woh + (size_t)DIM * DIM;

  k_cvt3<<<dim3(3584), 256, 0, stream>>>(x, xh, xl, in_proj_w, wih, wil,
                                         out_proj_w, woh, wol);

  kgemm_f16x3<1><<<dim3(32, 16), 256, 0, stream>>>(wih, wil, xh, xl,
                                                   xcraw, zbuf);
  k2_xproj_conv<<<dim3(64, KSL), 256, 0, stream>>>(xcraw, conv_w, conv_b, xc,
                                                   x_proj_w, part);
  k_red<<<dim3(384), 256, 0, stream>>>(part, xdbl);
  k3_dtproj<<<dim3(SEQ / 64, DIM / 64, BATCH), 256, 0, stream>>>(
      xdbl, dt_proj_w, dt_proj_b, delta);
  k_scan_fused<<<dim3(BATCH * DIM), 1024, 0, stream>>>(
      delta, xc, xdbl, A_log, D_param, zbuf, ybuf);
  k_gt<<<dim3(SEQ / 64, DIM / 64, BATCH), 256, 0, stream>>>(ybuf, gh, gl);
  kgemm_f16x3<0><<<dim3(8, 32), 256, 0, stream>>>(gh, gl, woh, wol,
                                                  out, nullptr);
}